// Round 1
// baseline (1270.933 us; speedup 1.0000x reference)
//
#include <hip/hip_runtime.h>
#include <math.h>

#define NNODES_FEAT 128   // node input dim
#define HD 128            // H*D = 4*32
#define H 4
#define D 32
#define EDGE_F 16         // edge input dim
#define NEG_SLOPE 0.2f

// ---------------- K0: w_eh[k][h] = sum_d W_edge[k*128 + h*32 + d] * attn_edge[h*32+d]
__global__ void k_wedge(const float* __restrict__ W_edge,
                        const float* __restrict__ attn_edge,
                        float* __restrict__ w_eh) {
    int t = threadIdx.x;            // 0..63
    int k = t >> 2;                 // 0..15
    int h = t & 3;                  // 0..3
    float s = 0.f;
    for (int d = 0; d < D; ++d)
        s += W_edge[k * HD + h * D + d] * attn_edge[h * D + d];
    w_eh[k * H + h] = s;
}

// ---------------- K1: tiled GEMM  A[N,128] @ (Wfc | Wres)[128,256]
// grid.y = 0,1 -> Wfc cols 0..63 / 64..127 -> feat
// grid.y = 2,3 -> Wres cols 0..63 / 64..127 -> out = res + bias
#define BM 64
#define BN 64
#define BK 16
__global__ __launch_bounds__(256) void k_gemm(
    const float* __restrict__ A, const float* __restrict__ Wfc,
    const float* __restrict__ Wres, const float* __restrict__ bias,
    float* __restrict__ feat, float* __restrict__ out, int N) {
    __shared__ float As[BK][BM + 4];   // transposed A tile, +4 keeps float4 align
    __shared__ float Bs[BK][BN];

    int tid = threadIdx.x;
    int tx = tid & 15, ty = tid >> 4;
    int m0 = blockIdx.x * BM;
    int cb = blockIdx.y;
    int colofs = (cb & 1) * BN;                      // 0 or 64
    const float* B = (cb < 2) ? (Wfc + colofs) : (Wres + colofs);

    float acc[4][4];
#pragma unroll
    for (int i = 0; i < 4; ++i)
#pragma unroll
        for (int j = 0; j < 4; ++j) acc[i][j] = 0.f;

    int li = tid * 4;
    int ar = li >> 4;          // A tile row 0..63
    int ak = li & 15;          // k offset {0,4,8,12}
    int br = li >> 6;          // B tile row 0..15
    int bc = li & 63;          // B col {0,4,...,60}

    for (int k0 = 0; k0 < NNODES_FEAT; k0 += BK) {
        int grow = m0 + ar;
        float4 av = make_float4(0.f, 0.f, 0.f, 0.f);
        if (grow < N) av = *(const float4*)(A + (long)grow * NNODES_FEAT + k0 + ak);
        As[ak + 0][ar] = av.x; As[ak + 1][ar] = av.y;
        As[ak + 2][ar] = av.z; As[ak + 3][ar] = av.w;

        float4 bv = *(const float4*)(B + (k0 + br) * HD + bc);
        *(float4*)(&Bs[br][bc]) = bv;
        __syncthreads();

#pragma unroll
        for (int k = 0; k < BK; ++k) {
            float4 a = *(const float4*)(&As[k][ty * 4]);
            float4 b = *(const float4*)(&Bs[k][tx * 4]);
            acc[0][0] += a.x * b.x; acc[0][1] += a.x * b.y; acc[0][2] += a.x * b.z; acc[0][3] += a.x * b.w;
            acc[1][0] += a.y * b.x; acc[1][1] += a.y * b.y; acc[1][2] += a.y * b.z; acc[1][3] += a.y * b.w;
            acc[2][0] += a.z * b.x; acc[2][1] += a.z * b.y; acc[2][2] += a.z * b.z; acc[2][3] += a.z * b.w;
            acc[3][0] += a.w * b.x; acc[3][1] += a.w * b.y; acc[3][2] += a.w * b.z; acc[3][3] += a.w * b.w;
        }
        __syncthreads();
    }

    int col = colofs + tx * 4;
    if (cb < 2) {
#pragma unroll
        for (int i = 0; i < 4; ++i) {
            int row = m0 + ty * 4 + i;
            if (row < N) {
                float4 v = make_float4(acc[i][0], acc[i][1], acc[i][2], acc[i][3]);
                *(float4*)(feat + (long)row * HD + col) = v;
            }
        }
    } else {
        float4 bv = *(const float4*)(bias + col);
#pragma unroll
        for (int i = 0; i < 4; ++i) {
            int row = m0 + ty * 4 + i;
            if (row < N) {
                float4 v = make_float4(acc[i][0] + bv.x, acc[i][1] + bv.y,
                                       acc[i][2] + bv.z, acc[i][3] + bv.w);
                *(float4*)(out + (long)row * HD + col) = v;
            }
        }
    }
}

// ---------------- K1b: a_src/a_dst [N,H] reductions over feat
__global__ __launch_bounds__(256) void k_attn_nodes(
    const float* __restrict__ feat, const float* __restrict__ attn_src,
    const float* __restrict__ attn_dst, float* __restrict__ a_src,
    float* __restrict__ a_dst, int N) {
    int g = blockIdx.x * 256 + threadIdx.x;
    int n = g >> 2, h = g & 3;
    if (n >= N) return;
    const float* f = feat + (long)n * HD + h * D;
    const float* w1 = attn_src + h * D;
    const float* w2 = attn_dst + h * D;
    float s1 = 0.f, s2 = 0.f;
#pragma unroll
    for (int d = 0; d < D; d += 4) {
        float4 fv = *(const float4*)(f + d);
        float4 u = *(const float4*)(w1 + d);
        float4 v = *(const float4*)(w2 + d);
        s1 += fv.x * u.x + fv.y * u.y + fv.z * u.z + fv.w * u.w;
        s2 += fv.x * v.x + fv.y * v.y + fv.z * v.z + fv.w * v.w;
    }
    a_src[n * H + h] = s1;
    a_dst[n * H + h] = s2;
}

// ---------------- K2: per-edge logits -> exp -> ex[E,4], atomic denom[N,4]
__global__ __launch_bounds__(256) void k_edges(
    const float* __restrict__ edge_inputs, const int* __restrict__ src,
    const int* __restrict__ dst, const float* __restrict__ w_eh,
    const float* __restrict__ a_src, const float* __restrict__ a_dst,
    float* __restrict__ exw, float* __restrict__ denom, int E) {
    __shared__ float weh_s[EDGE_F * H];
    if (threadIdx.x < EDGE_F * H) weh_s[threadIdx.x] = w_eh[threadIdx.x];
    __syncthreads();

    int e = blockIdx.x * 256 + threadIdx.x;
    if (e >= E) return;

    const float* x = edge_inputs + (long)e * EDGE_F;
    float ae[H] = {0.f, 0.f, 0.f, 0.f};
#pragma unroll
    for (int k = 0; k < EDGE_F; ++k) {
        float xv = x[k];
#pragma unroll
        for (int h = 0; h < H; ++h) ae[h] += xv * weh_s[k * H + h];
    }
    int s = src[e], d = dst[e];
    float4 as = *(const float4*)(a_src + s * H);
    float4 ad = *(const float4*)(a_dst + d * H);
    float ev[H];
    ev[0] = as.x + ad.x + ae[0];
    ev[1] = as.y + ad.y + ae[1];
    ev[2] = as.z + ad.z + ae[2];
    ev[3] = as.w + ad.w + ae[3];
#pragma unroll
    for (int h = 0; h < H; ++h) {
        float t = ev[h];
        t = t > 0.f ? t : NEG_SLOPE * t;
        ev[h] = __expf(t);
    }
    *(float4*)(exw + (long)e * H) = make_float4(ev[0], ev[1], ev[2], ev[3]);
#pragma unroll
    for (int h = 0; h < H; ++h) atomicAdd(denom + d * H + h, ev[h]);
}

// ---------------- K3: scatter messages; one wave per edge
__global__ __launch_bounds__(256) void k_scatter(
    const float* __restrict__ feat, const float* __restrict__ exw,
    const float* __restrict__ denom, const int* __restrict__ src,
    const int* __restrict__ dst, float* __restrict__ out, int E) {
    int wave = threadIdx.x >> 6;
    int lane = threadIdx.x & 63;
    int e = blockIdx.x * 4 + wave;
    if (e >= E) return;
    int s = src[e], d = dst[e];
    float4 exv = *(const float4*)(exw + (long)e * H);
    float4 dnv = *(const float4*)(denom + d * H);
    int h = lane >> 5;   // 0/1 for first 64 cols; heads 2/3 for the next 64
    float a0 = (h == 0) ? exv.x / dnv.x : exv.y / dnv.y;
    float a1 = (h == 0) ? exv.z / dnv.z : exv.w / dnv.w;
    float f0 = feat[(long)s * HD + lane];
    float f1 = feat[(long)s * HD + 64 + lane];
    atomicAdd(out + (long)d * HD + lane, f0 * a0);
    atomicAdd(out + (long)d * HD + 64 + lane, f1 * a1);
}

extern "C" void kernel_launch(void* const* d_in, const int* in_sizes, int n_in,
                              void* d_out, int out_size, void* d_ws, size_t ws_size,
                              hipStream_t stream) {
    const float* node_inputs = (const float*)d_in[0];
    const float* edge_inputs = (const float*)d_in[1];
    const int*   src         = (const int*)d_in[2];
    const int*   dst         = (const int*)d_in[3];
    const float* W_fc        = (const float*)d_in[4];
    const float* attn_src_p  = (const float*)d_in[5];
    const float* attn_dst_p  = (const float*)d_in[6];
    const float* W_edge      = (const float*)d_in[7];
    const float* attn_edge_p = (const float*)d_in[8];
    const float* W_res       = (const float*)d_in[9];
    const float* bias_p      = (const float*)d_in[10];

    int N = in_sizes[0] / NNODES_FEAT;   // 100000
    int E = in_sizes[2];                 // 1600000

    float* out = (float*)d_out;
    float* ws = (float*)d_ws;

    float* feat   = ws;                                 // N*128
    float* exw    = feat + (long)N * HD;                // E*4
    float* denom  = exw + (long)E * H;                  // N*4
    float* a_src  = denom + (long)N * H;                // N*4
    float* a_dst  = a_src + (long)N * H;                // N*4
    float* w_eh   = a_dst + (long)N * H;                // 64

    // zero the softmax denominator (ws is poisoned each call)
    hipMemsetAsync(denom, 0, (size_t)N * H * sizeof(float), stream);

    // K0: tiny fused edge-attention weight
    k_wedge<<<1, 64, 0, stream>>>(W_edge, attn_edge_p, w_eh);

    // K1: node GEMM -> feat, out = res + bias
    dim3 g1((N + BM - 1) / BM, 4);
    k_gemm<<<g1, 256, 0, stream>>>(node_inputs, W_fc, W_res, bias_p, feat, out, N);

    // K1b: per-node attention logits
    int nb = (N * H + 255) / 256;
    k_attn_nodes<<<nb, 256, 0, stream>>>(feat, attn_src_p, attn_dst_p, a_src, a_dst, N);

    // K2: per-edge logits -> exp + denom accumulation
    int eb = (E + 255) / 256;
    k_edges<<<eb, 256, 0, stream>>>(edge_inputs, src, dst, w_eh, a_src, a_dst,
                                    exw, denom, E);

    // K3: weighted scatter-aggregate
    int sb = (E + 3) / 4;
    k_scatter<<<sb, 256, 0, stream>>>(feat, exw, denom, src, dst, out, E);
}

// Round 2
// 654.567 us; speedup vs baseline: 1.9416x; 1.9416x over previous
//
#include <hip/hip_runtime.h>
#include <hip/hip_fp16.h>
#include <math.h>

#define NNODES_FEAT 128   // node input dim
#define HD 128            // H*D = 4*32
#define H 4
#define D 32
#define EDGE_F 16         // edge input dim
#define NEG_SLOPE 0.2f

// ---------------- K0: w_eh[k][h] = sum_d W_edge[k*128 + h*32 + d] * attn_edge[h*32+d]
__global__ void k_wedge(const float* __restrict__ W_edge,
                        const float* __restrict__ attn_edge,
                        float* __restrict__ w_eh) {
    int t = threadIdx.x;            // 0..63
    int k = t >> 2;                 // 0..15
    int h = t & 3;                  // 0..3
    float s = 0.f;
    for (int d = 0; d < D; ++d)
        s += W_edge[k * HD + h * D + d] * attn_edge[h * D + d];
    w_eh[k * H + h] = s;
}

// ---------------- K1: tiled GEMM  A[N,128] @ (Wfc | Wres)[128,256]
#define BM 64
#define BN 64
#define BK 16
__global__ __launch_bounds__(256) void k_gemm(
    const float* __restrict__ A, const float* __restrict__ Wfc,
    const float* __restrict__ Wres, const float* __restrict__ bias,
    float* __restrict__ feat, float* __restrict__ out, int N) {
    __shared__ float As[BK][BM + 4];
    __shared__ float Bs[BK][BN];

    int tid = threadIdx.x;
    int tx = tid & 15, ty = tid >> 4;
    int m0 = blockIdx.x * BM;
    int cb = blockIdx.y;
    int colofs = (cb & 1) * BN;
    const float* B = (cb < 2) ? (Wfc + colofs) : (Wres + colofs);

    float acc[4][4];
#pragma unroll
    for (int i = 0; i < 4; ++i)
#pragma unroll
        for (int j = 0; j < 4; ++j) acc[i][j] = 0.f;

    int li = tid * 4;
    int ar = li >> 4;
    int ak = li & 15;
    int br = li >> 6;
    int bc = li & 63;

    for (int k0 = 0; k0 < NNODES_FEAT; k0 += BK) {
        int grow = m0 + ar;
        float4 av = make_float4(0.f, 0.f, 0.f, 0.f);
        if (grow < N) av = *(const float4*)(A + (long)grow * NNODES_FEAT + k0 + ak);
        As[ak + 0][ar] = av.x; As[ak + 1][ar] = av.y;
        As[ak + 2][ar] = av.z; As[ak + 3][ar] = av.w;

        float4 bv = *(const float4*)(B + (k0 + br) * HD + bc);
        *(float4*)(&Bs[br][bc]) = bv;
        __syncthreads();

#pragma unroll
        for (int k = 0; k < BK; ++k) {
            float4 a = *(const float4*)(&As[k][ty * 4]);
            float4 b = *(const float4*)(&Bs[k][tx * 4]);
            acc[0][0] += a.x * b.x; acc[0][1] += a.x * b.y; acc[0][2] += a.x * b.z; acc[0][3] += a.x * b.w;
            acc[1][0] += a.y * b.x; acc[1][1] += a.y * b.y; acc[1][2] += a.y * b.z; acc[1][3] += a.y * b.w;
            acc[2][0] += a.z * b.x; acc[2][1] += a.z * b.y; acc[2][2] += a.z * b.z; acc[2][3] += a.z * b.w;
            acc[3][0] += a.w * b.x; acc[3][1] += a.w * b.y; acc[3][2] += a.w * b.z; acc[3][3] += a.w * b.w;
        }
        __syncthreads();
    }

    int col = colofs + tx * 4;
    if (cb < 2) {
#pragma unroll
        for (int i = 0; i < 4; ++i) {
            int row = m0 + ty * 4 + i;
            if (row < N) {
                float4 v = make_float4(acc[i][0], acc[i][1], acc[i][2], acc[i][3]);
                *(float4*)(feat + (long)row * HD + col) = v;
            }
        }
    } else {
        float4 bv = *(const float4*)(bias + col);
#pragma unroll
        for (int i = 0; i < 4; ++i) {
            int row = m0 + ty * 4 + i;
            if (row < N) {
                float4 v = make_float4(acc[i][0] + bv.x, acc[i][1] + bv.y,
                                       acc[i][2] + bv.z, acc[i][3] + bv.w);
                *(float4*)(out + (long)row * HD + col) = v;
            }
        }
    }
}

// ---------------- K1b: a_src/a_dst [N,H] reductions over feat
__global__ __launch_bounds__(256) void k_attn_nodes(
    const float* __restrict__ feat, const float* __restrict__ attn_src,
    const float* __restrict__ attn_dst, float* __restrict__ a_src,
    float* __restrict__ a_dst, int N) {
    int g = blockIdx.x * 256 + threadIdx.x;
    int n = g >> 2, h = g & 3;
    if (n >= N) return;
    const float* f = feat + (long)n * HD + h * D;
    const float* w1 = attn_src + h * D;
    const float* w2 = attn_dst + h * D;
    float s1 = 0.f, s2 = 0.f;
#pragma unroll
    for (int d = 0; d < D; d += 4) {
        float4 fv = *(const float4*)(f + d);
        float4 u = *(const float4*)(w1 + d);
        float4 v = *(const float4*)(w2 + d);
        s1 += fv.x * u.x + fv.y * u.y + fv.z * u.z + fv.w * u.w;
        s2 += fv.x * v.x + fv.y * v.y + fv.z * v.z + fv.w * v.w;
    }
    a_src[n * H + h] = s1;
    a_dst[n * H + h] = s2;
}

// ---------------- K2a: in-degree count
__global__ __launch_bounds__(256) void k_count(const int* __restrict__ dst,
                                               int* __restrict__ deg, int E) {
    int e = blockIdx.x * 256 + threadIdx.x;
    if (e < E) atomicAdd(deg + dst[e], 1);
}

// ---------------- K2b: scan, block partial sums (1024 elems / block)
__global__ __launch_bounds__(256) void k_scan_partial(
    const int* __restrict__ deg, int* __restrict__ partial, int N) {
    __shared__ int sdata[256];
    int t = threadIdx.x;
    int base = blockIdx.x * 1024 + t * 4;
    int s = 0;
#pragma unroll
    for (int j = 0; j < 4; ++j) { int i = base + j; if (i < N) s += deg[i]; }
    sdata[t] = s;
    __syncthreads();
    for (int off = 128; off > 0; off >>= 1) {
        if (t < off) sdata[t] += sdata[t + off];
        __syncthreads();
    }
    if (t == 0) partial[blockIdx.x] = sdata[0];
}

// ---------------- K2c: scan top level (single block), exclusive over partials
__global__ __launch_bounds__(256) void k_scan_top(
    int* __restrict__ partial, int* __restrict__ offs, int nb, int N) {
    __shared__ int sdata[256];
    int t = threadIdx.x;
    int v = (t < nb) ? partial[t] : 0;
    sdata[t] = v;
    __syncthreads();
    for (int off = 1; off < 256; off <<= 1) {
        int add = (t >= off) ? sdata[t - off] : 0;
        __syncthreads();
        sdata[t] += add;
        __syncthreads();
    }
    int excl = (t == 0) ? 0 : sdata[t - 1];
    if (t < nb) partial[t] = excl;
    if (t == nb - 1) offs[N] = sdata[t];   // total = E
}

// ---------------- K2d: final scan; offs aliases deg (in-place, block-local)
__global__ __launch_bounds__(256) void k_scan_final(
    int* __restrict__ deg_offs, const int* __restrict__ partial,
    int* __restrict__ cursor, int N) {
    __shared__ int sdata[256];
    int t = threadIdx.x;
    int base = blockIdx.x * 1024 + t * 4;
    int v[4]; int s = 0;
#pragma unroll
    for (int j = 0; j < 4; ++j) { int i = base + j; v[j] = (i < N) ? deg_offs[i] : 0; s += v[j]; }
    sdata[t] = s;
    __syncthreads();
    for (int off = 1; off < 256; off <<= 1) {
        int add = (t >= off) ? sdata[t - off] : 0;
        __syncthreads();
        sdata[t] += add;
        __syncthreads();
    }
    int excl = partial[blockIdx.x] + ((t == 0) ? 0 : sdata[t - 1]);
#pragma unroll
    for (int j = 0; j < 4; ++j) {
        int i = base + j;
        if (i < N) { deg_offs[i] = excl; cursor[i] = excl; excl += v[j]; }
    }
}

// ---------------- K3: per-edge logits -> exp -> permuted (esrc, exph)
__global__ __launch_bounds__(256) void k_edge_fill(
    const float* __restrict__ edge_inputs, const int* __restrict__ src,
    const int* __restrict__ dst, const float* __restrict__ w_eh,
    const float* __restrict__ a_src, const float* __restrict__ a_dst,
    int* __restrict__ cursor, int* __restrict__ esrc,
    __half* __restrict__ exph, int E) {
    __shared__ float weh_s[EDGE_F * H];
    if (threadIdx.x < EDGE_F * H) weh_s[threadIdx.x] = w_eh[threadIdx.x];
    __syncthreads();

    int e = blockIdx.x * 256 + threadIdx.x;
    if (e >= E) return;

    const float* x = edge_inputs + (long)e * EDGE_F;
    float ae[H] = {0.f, 0.f, 0.f, 0.f};
#pragma unroll
    for (int k = 0; k < EDGE_F; ++k) {
        float xv = x[k];
#pragma unroll
        for (int h = 0; h < H; ++h) ae[h] += xv * weh_s[k * H + h];
    }
    int s = src[e], d = dst[e];
    float4 as = *(const float4*)(a_src + s * H);
    float4 ad = *(const float4*)(a_dst + d * H);
    float ev[H];
    ev[0] = as.x + ad.x + ae[0];
    ev[1] = as.y + ad.y + ae[1];
    ev[2] = as.z + ad.z + ae[2];
    ev[3] = as.w + ad.w + ae[3];
#pragma unroll
    for (int h = 0; h < H; ++h) {
        float t = ev[h];
        t = t > 0.f ? t : NEG_SLOPE * t;
        ev[h] = __expf(t);
    }
    int pos = atomicAdd(cursor + d, 1);
    esrc[pos] = s;
    union { __half2 h2[2]; float2 f2; } u;
    u.h2[0] = __floats2half2_rn(ev[0], ev[1]);
    u.h2[1] = __floats2half2_rn(ev[2], ev[3]);
    *(float2*)(exph + (size_t)pos * 4) = u.f2;
}

// ---------------- K4: per-dst aggregation, one wave per node, no atomics
__global__ __launch_bounds__(256) void k_aggr(
    const float* __restrict__ feat, const __half* __restrict__ exph,
    const int* __restrict__ esrc, const int* __restrict__ offs,
    float* __restrict__ out, int N) {
    int wave = threadIdx.x >> 6;
    int lane = threadIdx.x & 63;
    int n = blockIdx.x * 4 + wave;
    if (n >= N) return;
    int beg = offs[n], end = offs[n + 1];
    if (end <= beg) return;                 // no in-edges: out keeps res+bias
    int h0 = lane >> 5;                     // head for col0 (0/1); col1 head = 2+h0
    float num0 = 0.f, num1 = 0.f, den0 = 0.f, den1 = 0.f;
    for (int i = beg; i < end; ++i) {
        int s = esrc[i];
        float e0 = __half2float(exph[(size_t)i * 4 + h0]);
        float e1 = __half2float(exph[(size_t)i * 4 + 2 + h0]);
        float f0 = feat[(long)s * HD + lane];
        float f1 = feat[(long)s * HD + 64 + lane];
        num0 += e0 * f0; num1 += e1 * f1;
        den0 += e0;      den1 += e1;
    }
    long o = (long)n * HD;
    out[o + lane]      += num0 / den0;
    out[o + 64 + lane] += num1 / den1;
}

extern "C" void kernel_launch(void* const* d_in, const int* in_sizes, int n_in,
                              void* d_out, int out_size, void* d_ws, size_t ws_size,
                              hipStream_t stream) {
    const float* node_inputs = (const float*)d_in[0];
    const float* edge_inputs = (const float*)d_in[1];
    const int*   src         = (const int*)d_in[2];
    const int*   dst         = (const int*)d_in[3];
    const float* W_fc        = (const float*)d_in[4];
    const float* attn_src_p  = (const float*)d_in[5];
    const float* attn_dst_p  = (const float*)d_in[6];
    const float* W_edge      = (const float*)d_in[7];
    const float* attn_edge_p = (const float*)d_in[8];
    const float* W_res       = (const float*)d_in[9];
    const float* bias_p      = (const float*)d_in[10];

    int N = in_sizes[0] / NNODES_FEAT;   // 100000
    int E = in_sizes[2];                 // 1600000

    float* out = (float*)d_out;
    float* ws = (float*)d_ws;

    // ---- workspace layout (all 8B-aligned) ----
    float*  feat    = ws;                                  // N*128 f
    float*  a_src   = feat + (size_t)N * HD;               // N*4 f
    float*  a_dst   = a_src + (size_t)N * H;               // N*4 f
    float*  w_eh    = a_dst + (size_t)N * H;               // 64 f
    int*    deg     = (int*)(w_eh + 64);                   // N+2 (becomes offs)
    int*    offs    = deg;                                 // alias (in-place scan)
    int*    cursor  = deg + (N + 2);                       // N
    int*    partial = cursor + N;                          // 128
    int*    esrc    = partial + 128;                       // E
    __half* exph    = (__half*)(esrc + (size_t)E);         // E*4 halves

    // zero degree counters (ws is poisoned each call)
    hipMemsetAsync(deg, 0, (size_t)(N + 2) * sizeof(int), stream);

    // K0: fused edge-attention weight (16x4)
    k_wedge<<<1, 64, 0, stream>>>(W_edge, attn_edge_p, w_eh);

    // K1: node GEMM -> feat, out = res + bias
    dim3 g1((N + BM - 1) / BM, 4);
    k_gemm<<<g1, 256, 0, stream>>>(node_inputs, W_fc, W_res, bias_p, feat, out, N);

    // K1b: per-node attention logits
    int nb = (N * H + 255) / 256;
    k_attn_nodes<<<nb, 256, 0, stream>>>(feat, attn_src_p, attn_dst_p, a_src, a_dst, N);

    // K2: CSR by dst — count, scan, (fill happens in K3)
    int eb = (E + 255) / 256;
    k_count<<<eb, 256, 0, stream>>>(dst, deg, E);
    int sb = (N + 1023) / 1024;   // 98 blocks
    k_scan_partial<<<sb, 256, 0, stream>>>(deg, partial, N);
    k_scan_top<<<1, 256, 0, stream>>>(partial, offs, sb, N);
    k_scan_final<<<sb, 256, 0, stream>>>(deg, partial, cursor, N);

    // K3: edge logits -> exp, scattered into dst-bucketed order
    k_edge_fill<<<eb, 256, 0, stream>>>(edge_inputs, src, dst, w_eh, a_src, a_dst,
                                        cursor, esrc, exph, E);

    // K4: aggregation, one wave per node, no atomics
    int ab = (N + 3) / 4;
    k_aggr<<<ab, 256, 0, stream>>>(feat, exph, esrc, offs, out, N);
}

// Round 3
// 551.823 us; speedup vs baseline: 2.3032x; 1.1862x over previous
//
#include <hip/hip_runtime.h>
#include <math.h>

#define NNODES_FEAT 128   // node input dim
#define HD 128            // H*D = 4*32
#define H 4
#define D 32
#define EDGE_F 16         // edge input dim
#define NEG_SLOPE 0.2f

typedef _Float16 f16;
typedef _Float16 f16x2 __attribute__((ext_vector_type(2)));
typedef _Float16 f16x4 __attribute__((ext_vector_type(4)));
typedef _Float16 f16x8 __attribute__((ext_vector_type(8)));
typedef float f32x4 __attribute__((ext_vector_type(4)));

// ---------------- K0: w_eh[k][h] = sum_d W_edge[k*128 + h*32 + d] * attn_edge[h*32+d]
__global__ void k_wedge(const float* __restrict__ W_edge,
                        const float* __restrict__ attn_edge,
                        float* __restrict__ w_eh) {
    int t = threadIdx.x;            // 0..63
    int k = t >> 2;                 // 0..15
    int h = t & 3;                  // 0..3
    float s = 0.f;
    for (int d = 0; d < D; ++d)
        s += W_edge[k * HD + h * D + d] * attn_edge[h * D + d];
    w_eh[k * H + h] = s;
}

// ---------------- K0b: cast node_inputs fp32 -> fp16
__global__ __launch_bounds__(256) void k_cast(const float* __restrict__ A,
                                              f16* __restrict__ A16, int n) {
    int i = (blockIdx.x * 256 + threadIdx.x) * 4;
    if (i >= n) return;
    float4 v = *(const float4*)(A + i);
    f16x4 h = {(f16)v.x, (f16)v.y, (f16)v.z, (f16)v.w};
    *(f16x4*)(A16 + i) = h;
}

// ---------------- K0c: Wt[n][k] = (n<128 ? Wfc[k][n] : Wres[k][n-128]) as fp16
__global__ __launch_bounds__(256) void k_wt(const float* __restrict__ Wfc,
                                            const float* __restrict__ Wres,
                                            f16* __restrict__ Wt) {
    int i = blockIdx.x * 256 + threadIdx.x;    // 0..32767
    int n = i >> 7, k = i & 127;
    float v = (n < 128) ? Wfc[k * HD + n] : Wres[k * HD + (n - 128)];
    Wt[(size_t)n * 128 + k] = (f16)v;
}

// ---------------- K1: MFMA GEMM  A16[N,128] @ Wt^T -> feat16 (cb=0) / out (cb=1)
// block: 256 thr = 4 waves, tile M=64 x Ncols=128, K=128 fully staged
#define LDK 136   // padded leading dim (halves): 272 B -> 2-way LDS conflict (free)
__global__ __launch_bounds__(256) void k_gemm_mfma(
    const f16* __restrict__ A16, const f16* __restrict__ Wt,
    const float* __restrict__ bias, f16* __restrict__ feat16,
    float* __restrict__ out, int N) {
    __shared__ f16 As[64 * LDK];
    __shared__ f16 Bs[128 * LDK];
    int tid = threadIdx.x;
    int wave = tid >> 6, lane = tid & 63;
    int m0 = blockIdx.x * 64;
    int cb = blockIdx.y;

    // stage A tile: 64 rows x 128 halves (16B chunks, coalesced)
    for (int c = tid; c < 64 * 16; c += 256) {
        int r = c >> 4, cc = (c & 15) * 8;
        int gr = m0 + r;
        float4 v = make_float4(0.f, 0.f, 0.f, 0.f);
        if (gr < N) v = *(const float4*)(A16 + (size_t)gr * 128 + cc);
        *(float4*)(&As[r * LDK + cc]) = v;
    }
    // stage B tile: rows = output cols [cb*128, cb*128+128), each 128 halves
    const f16* Wblk = Wt + (size_t)cb * 128 * 128;
    for (int c = tid; c < 128 * 16; c += 256) {
        int r = c >> 4, cc = (c & 15) * 8;
        float4 v = *(const float4*)(Wblk + (size_t)r * 128 + cc);
        *(float4*)(&Bs[r * LDK + cc]) = v;
    }
    __syncthreads();

    int am = lane & 15, aq = lane >> 4;
    f32x4 acc[8];
#pragma unroll
    for (int nt = 0; nt < 8; ++nt) acc[nt] = (f32x4){0.f, 0.f, 0.f, 0.f};

    int arow = wave * 16 + am;
#pragma unroll
    for (int kc = 0; kc < 4; ++kc) {
        f16x8 a = *(const f16x8*)(&As[arow * LDK + kc * 32 + aq * 8]);
#pragma unroll
        for (int nt = 0; nt < 8; ++nt) {
            f16x8 b = *(const f16x8*)(&Bs[(nt * 16 + am) * LDK + kc * 32 + aq * 8]);
            acc[nt] = __builtin_amdgcn_mfma_f32_16x16x32_f16(a, b, acc[nt], 0, 0, 0);
        }
    }

    // epilogue: D row=(lane>>4)*4+r, col=lane&15 within each 16x16 tile
    int orow0 = m0 + wave * 16 + aq * 4;
    if (cb == 0) {
#pragma unroll
        for (int nt = 0; nt < 8; ++nt) {
            int col = nt * 16 + am;
#pragma unroll
            for (int r = 0; r < 4; ++r) {
                int row = orow0 + r;
                if (row < N) feat16[(size_t)row * 128 + col] = (f16)acc[nt][r];
            }
        }
    } else {
#pragma unroll
        for (int nt = 0; nt < 8; ++nt) {
            int col = nt * 16 + am;
            float bv = bias[col];
#pragma unroll
            for (int r = 0; r < 4; ++r) {
                int row = orow0 + r;
                if (row < N) out[(size_t)row * 128 + col] = acc[nt][r] + bv;
            }
        }
    }
}

// ---------------- K1b: a_src/a_dst [N,H] reductions over feat16
__global__ __launch_bounds__(256) void k_attn_nodes(
    const f16* __restrict__ feat16, const float* __restrict__ attn_src,
    const float* __restrict__ attn_dst, float* __restrict__ a_src,
    float* __restrict__ a_dst, int N) {
    int g = blockIdx.x * 256 + threadIdx.x;
    int n = g >> 2, h = g & 3;
    if (n >= N) return;
    const f16* f = feat16 + (size_t)n * HD + h * D;
    const float* w1 = attn_src + h * D;
    const float* w2 = attn_dst + h * D;
    float s1 = 0.f, s2 = 0.f;
#pragma unroll
    for (int d = 0; d < D; d += 2) {
        f16x2 fv = *(const f16x2*)(f + d);
        float f0 = (float)fv.x, f1 = (float)fv.y;
        s1 += f0 * w1[d] + f1 * w1[d + 1];
        s2 += f0 * w2[d] + f1 * w2[d + 1];
    }
    a_src[n * H + h] = s1;
    a_dst[n * H + h] = s2;
}

// ---------------- K2a: in-degree count
__global__ __launch_bounds__(256) void k_count(const int* __restrict__ dst,
                                               int* __restrict__ deg, int E) {
    int e = blockIdx.x * 256 + threadIdx.x;
    if (e < E) atomicAdd(deg + dst[e], 1);
}

// ---------------- K2b: scan, block partial sums (1024 elems / block)
__global__ __launch_bounds__(256) void k_scan_partial(
    const int* __restrict__ deg, int* __restrict__ partial, int N) {
    __shared__ int sdata[256];
    int t = threadIdx.x;
    int base = blockIdx.x * 1024 + t * 4;
    int s = 0;
#pragma unroll
    for (int j = 0; j < 4; ++j) { int i = base + j; if (i < N) s += deg[i]; }
    sdata[t] = s;
    __syncthreads();
    for (int off = 128; off > 0; off >>= 1) {
        if (t < off) sdata[t] += sdata[t + off];
        __syncthreads();
    }
    if (t == 0) partial[blockIdx.x] = sdata[0];
}

// ---------------- K2c: scan top level (single block), exclusive over partials
__global__ __launch_bounds__(256) void k_scan_top(
    int* __restrict__ partial, int* __restrict__ offs, int nb, int N) {
    __shared__ int sdata[256];
    int t = threadIdx.x;
    int v = (t < nb) ? partial[t] : 0;
    sdata[t] = v;
    __syncthreads();
    for (int off = 1; off < 256; off <<= 1) {
        int add = (t >= off) ? sdata[t - off] : 0;
        __syncthreads();
        sdata[t] += add;
        __syncthreads();
    }
    int excl = (t == 0) ? 0 : sdata[t - 1];
    if (t < nb) partial[t] = excl;
    if (t == nb - 1) offs[N] = sdata[t];   // total = E
}

// ---------------- K2d: final scan; offs aliases deg (in-place, block-local)
__global__ __launch_bounds__(256) void k_scan_final(
    int* __restrict__ deg_offs, const int* __restrict__ partial,
    int* __restrict__ cursor, int N) {
    __shared__ int sdata[256];
    int t = threadIdx.x;
    int base = blockIdx.x * 1024 + t * 4;
    int v[4]; int s = 0;
#pragma unroll
    for (int j = 0; j < 4; ++j) { int i = base + j; v[j] = (i < N) ? deg_offs[i] : 0; s += v[j]; }
    sdata[t] = s;
    __syncthreads();
    for (int off = 1; off < 256; off <<= 1) {
        int add = (t >= off) ? sdata[t - off] : 0;
        __syncthreads();
        sdata[t] += add;
        __syncthreads();
    }
    int excl = partial[blockIdx.x] + ((t == 0) ? 0 : sdata[t - 1]);
#pragma unroll
    for (int j = 0; j < 4; ++j) {
        int i = base + j;
        if (i < N) { deg_offs[i] = excl; cursor[i] = excl; excl += v[j]; }
    }
}

// ---------------- K3: per-edge logits -> exp -> permuted (esrc, exph)
__global__ __launch_bounds__(256) void k_edge_fill(
    const float* __restrict__ edge_inputs, const int* __restrict__ src,
    const int* __restrict__ dst, const float* __restrict__ w_eh,
    const float* __restrict__ a_src, const float* __restrict__ a_dst,
    int* __restrict__ cursor, int* __restrict__ esrc,
    f16* __restrict__ exph, int E) {
    __shared__ float weh_s[EDGE_F * H];
    if (threadIdx.x < EDGE_F * H) weh_s[threadIdx.x] = w_eh[threadIdx.x];
    __syncthreads();

    int e = blockIdx.x * 256 + threadIdx.x;
    if (e >= E) return;

    const float* x = edge_inputs + (long)e * EDGE_F;
    float ae[H] = {0.f, 0.f, 0.f, 0.f};
#pragma unroll
    for (int k = 0; k < EDGE_F; ++k) {
        float xv = x[k];
#pragma unroll
        for (int h = 0; h < H; ++h) ae[h] += xv * weh_s[k * H + h];
    }
    int s = src[e], d = dst[e];
    float4 as = *(const float4*)(a_src + s * H);
    float4 ad = *(const float4*)(a_dst + d * H);
    float ev[H];
    ev[0] = as.x + ad.x + ae[0];
    ev[1] = as.y + ad.y + ae[1];
    ev[2] = as.z + ad.z + ae[2];
    ev[3] = as.w + ad.w + ae[3];
#pragma unroll
    for (int h = 0; h < H; ++h) {
        float t = ev[h];
        t = t > 0.f ? t : NEG_SLOPE * t;
        ev[h] = __expf(t);
    }
    int pos = atomicAdd(cursor + d, 1);
    esrc[pos] = s;
    f16x4 hv = {(f16)ev[0], (f16)ev[1], (f16)ev[2], (f16)ev[3]};
    *(f16x4*)(exph + (size_t)pos * 4) = hv;
}

// ---------------- K4: per-dst aggregation; wave/node, lane = 2 adjacent cols
__global__ __launch_bounds__(256) void k_aggr(
    const f16* __restrict__ feat16, const f16* __restrict__ exph,
    const int* __restrict__ esrc, const int* __restrict__ offs,
    float* __restrict__ out, int N) {
    int wave = threadIdx.x >> 6;
    int lane = threadIdx.x & 63;
    int n = blockIdx.x * 4 + wave;
    if (n >= N) return;
    int beg = offs[n], end = offs[n + 1];
    if (end <= beg) return;                 // no in-edges: out keeps res+bias
    int h = lane >> 4;                      // head of cols {2l, 2l+1}
    size_t c0 = (size_t)2 * lane;
    float num0 = 0.f, num1 = 0.f, den = 0.f;
    int i = beg;
    for (; i + 1 < end; i += 2) {
        int s0 = esrc[i], s1 = esrc[i + 1];
        float e0 = (float)exph[(size_t)i * 4 + h];
        float e1 = (float)exph[(size_t)(i + 1) * 4 + h];
        f16x2 f0 = *(const f16x2*)(feat16 + (size_t)s0 * HD + c0);
        f16x2 f1 = *(const f16x2*)(feat16 + (size_t)s1 * HD + c0);
        num0 += e0 * (float)f0.x + e1 * (float)f1.x;
        num1 += e0 * (float)f0.y + e1 * (float)f1.y;
        den += e0 + e1;
    }
    if (i < end) {
        int s0 = esrc[i];
        float e0 = (float)exph[(size_t)i * 4 + h];
        f16x2 f0 = *(const f16x2*)(feat16 + (size_t)s0 * HD + c0);
        num0 += e0 * (float)f0.x;
        num1 += e0 * (float)f0.y;
        den += e0;
    }
    float inv = 1.f / den;
    size_t o = (size_t)n * HD + c0;
    float2 v = *(float2*)(out + o);
    v.x += num0 * inv;
    v.y += num1 * inv;
    *(float2*)(out + o) = v;
}

extern "C" void kernel_launch(void* const* d_in, const int* in_sizes, int n_in,
                              void* d_out, int out_size, void* d_ws, size_t ws_size,
                              hipStream_t stream) {
    const float* node_inputs = (const float*)d_in[0];
    const float* edge_inputs = (const float*)d_in[1];
    const int*   src         = (const int*)d_in[2];
    const int*   dst         = (const int*)d_in[3];
    const float* W_fc        = (const float*)d_in[4];
    const float* attn_src_p  = (const float*)d_in[5];
    const float* attn_dst_p  = (const float*)d_in[6];
    const float* W_edge      = (const float*)d_in[7];
    const float* attn_edge_p = (const float*)d_in[8];
    const float* W_res       = (const float*)d_in[9];
    const float* bias_p      = (const float*)d_in[10];

    int N = in_sizes[0] / NNODES_FEAT;   // 100000
    int E = in_sizes[2];                 // 1600000

    float* out = (float*)d_out;

    // ---- workspace layout ----
    f16*    A16     = (f16*)d_ws;                          // N*128 halves
    f16*    feat16  = A16 + (size_t)N * HD;                // N*128 halves
    f16*    Wt      = feat16 + (size_t)N * HD;             // 256*128 halves
    float*  a_src   = (float*)(Wt + 256 * 128);            // N*4
    float*  a_dst   = a_src + (size_t)N * H;               // N*4
    float*  w_eh    = a_dst + (size_t)N * H;               // 64
    int*    deg     = (int*)(w_eh + 64);                   // N+2 (becomes offs)
    int*    offs    = deg;                                 // alias
    int*    cursor  = deg + (N + 2);                       // N
    int*    partial = cursor + N;                          // 128
    int*    esrc    = partial + 128;                       // E
    f16*    exph    = (f16*)(esrc + (size_t)E);            // E*4 halves

    hipMemsetAsync(deg, 0, (size_t)(N + 2) * sizeof(int), stream);

    // precompute small tensors
    k_wedge<<<1, 64, 0, stream>>>(W_edge, attn_edge_p, w_eh);
    k_wt<<<(256 * 128) / 256, 256, 0, stream>>>(W_fc, W_res, Wt);
    k_cast<<<(N * HD / 4 + 255) / 256, 256, 0, stream>>>(node_inputs, A16, N * HD);

    // MFMA GEMM -> feat16 (cb=0), out = res + bias (cb=1)
    dim3 g1((N + 63) / 64, 2);
    k_gemm_mfma<<<g1, 256, 0, stream>>>(A16, Wt, bias_p, feat16, out, N);

    // per-node attention logits
    int nb = (N * H + 255) / 256;
    k_attn_nodes<<<nb, 256, 0, stream>>>(feat16, attn_src_p, attn_dst_p, a_src, a_dst, N);

    // CSR by dst
    int eb = (E + 255) / 256;
    k_count<<<eb, 256, 0, stream>>>(dst, deg, E);
    int sb = (N + 1023) / 1024;   // 98 blocks
    k_scan_partial<<<sb, 256, 0, stream>>>(deg, partial, N);
    k_scan_top<<<1, 256, 0, stream>>>(partial, offs, sb, N);
    k_scan_final<<<sb, 256, 0, stream>>>(deg, partial, cursor, N);

    // edge logits -> exp, scattered into dst-bucketed order
    k_edge_fill<<<eb, 256, 0, stream>>>(edge_inputs, src, dst, w_eh, a_src, a_dst,
                                        cursor, esrc, exph, E);

    // aggregation
    int ab = (N + 3) / 4;
    k_aggr<<<ab, 256, 0, stream>>>(feat16, exph, esrc, offs, out, N);
}

// Round 4
// 516.324 us; speedup vs baseline: 2.4615x; 1.0688x over previous
//
#include <hip/hip_runtime.h>
#include <math.h>

#define NNODES_FEAT 128   // node input dim
#define HD 128            // H*D = 4*32
#define H 4
#define D 32
#define EDGE_F 16         // edge input dim
#define NEG_SLOPE 0.2f

typedef _Float16 f16;
typedef _Float16 f16x2 __attribute__((ext_vector_type(2)));
typedef _Float16 f16x4 __attribute__((ext_vector_type(4)));
typedef _Float16 f16x8 __attribute__((ext_vector_type(8)));
typedef float f32x4 __attribute__((ext_vector_type(4)));

union ExPack { float2 f; f16x4 h; };

// ---------------- K0: w_eh[k][h] = sum_d W_edge[k*128 + h*32 + d] * attn_edge[h*32+d]
__global__ void k_wedge(const float* __restrict__ W_edge,
                        const float* __restrict__ attn_edge,
                        float* __restrict__ w_eh) {
    int t = threadIdx.x;            // 0..63
    int k = t >> 2;                 // 0..15
    int h = t & 3;                  // 0..3
    float s = 0.f;
    for (int d = 0; d < D; ++d)
        s += W_edge[k * HD + h * D + d] * attn_edge[h * D + d];
    w_eh[k * H + h] = s;
}

// ---------------- K0c: Wt[n][k] = (n<128 ? Wfc[k][n] : Wres[k][n-128]) as fp16
__global__ __launch_bounds__(256) void k_wt(const float* __restrict__ Wfc,
                                            const float* __restrict__ Wres,
                                            f16* __restrict__ Wt) {
    int i = blockIdx.x * 256 + threadIdx.x;    // 0..32767
    int n = i >> 7, k = i & 127;
    float v = (n < 128) ? Wfc[k * HD + n] : Wres[k * HD + (n - 128)];
    Wt[(size_t)n * 128 + k] = (f16)v;
}

// ---------------- K1: MFMA GEMM  A[N,128](fp32) @ Wt^T -> feat16 (cb=0) / out (cb=1)
// block: 256 thr = 4 waves, tile M=64 x Ncols=128, K=128 fully staged
#define LDK 136   // padded leading dim (halves)
__global__ __launch_bounds__(256) void k_gemm_mfma(
    const float* __restrict__ A, const f16* __restrict__ Wt,
    const float* __restrict__ bias, f16* __restrict__ feat16,
    float* __restrict__ out, int N) {
    __shared__ f16 As[64 * LDK];
    __shared__ f16 Bs[128 * LDK];
    int tid = threadIdx.x;
    int wave = tid >> 6, lane = tid & 63;
    int m0 = blockIdx.x * 64;
    int cb = blockIdx.y;

    // stage A tile: 64 rows x 128 floats, convert fp32->fp16 on LDS store
    for (int c = tid; c < 64 * 32; c += 256) {
        int r = c >> 5, cc = (c & 31) * 4;
        int gr = m0 + r;
        float4 v = make_float4(0.f, 0.f, 0.f, 0.f);
        if (gr < N) v = *(const float4*)(A + (size_t)gr * 128 + cc);
        f16x4 h = {(f16)v.x, (f16)v.y, (f16)v.z, (f16)v.w};
        *(f16x4*)(&As[r * LDK + cc]) = h;
    }
    // stage B tile: rows = output cols [cb*128, cb*128+128), each 128 halves
    const f16* Wblk = Wt + (size_t)cb * 128 * 128;
    for (int c = tid; c < 128 * 16; c += 256) {
        int r = c >> 4, cc = (c & 15) * 8;
        float4 v = *(const float4*)(Wblk + (size_t)r * 128 + cc);
        *(float4*)(&Bs[r * LDK + cc]) = v;
    }
    __syncthreads();

    int am = lane & 15, aq = lane >> 4;
    f32x4 acc[8];
#pragma unroll
    for (int nt = 0; nt < 8; ++nt) acc[nt] = (f32x4){0.f, 0.f, 0.f, 0.f};

    int arow = wave * 16 + am;
#pragma unroll
    for (int kc = 0; kc < 4; ++kc) {
        f16x8 a = *(const f16x8*)(&As[arow * LDK + kc * 32 + aq * 8]);
#pragma unroll
        for (int nt = 0; nt < 8; ++nt) {
            f16x8 b = *(const f16x8*)(&Bs[(nt * 16 + am) * LDK + kc * 32 + aq * 8]);
            acc[nt] = __builtin_amdgcn_mfma_f32_16x16x32_f16(a, b, acc[nt], 0, 0, 0);
        }
    }

    // epilogue: D row=(lane>>4)*4+r, col=lane&15 within each 16x16 tile
    int orow0 = m0 + wave * 16 + aq * 4;
    if (cb == 0) {
#pragma unroll
        for (int nt = 0; nt < 8; ++nt) {
            int col = nt * 16 + am;
#pragma unroll
            for (int r = 0; r < 4; ++r) {
                int row = orow0 + r;
                if (row < N) feat16[(size_t)row * 128 + col] = (f16)acc[nt][r];
            }
        }
    } else {
#pragma unroll
        for (int nt = 0; nt < 8; ++nt) {
            int col = nt * 16 + am;
            float bv = bias[col];
#pragma unroll
            for (int r = 0; r < 4; ++r) {
                int row = orow0 + r;
                if (row < N) out[(size_t)row * 128 + col] = acc[nt][r] + bv;
            }
        }
    }
}

// ---------------- K1b: a_src/a_dst [N,H] reductions over feat16
__global__ __launch_bounds__(256) void k_attn_nodes(
    const f16* __restrict__ feat16, const float* __restrict__ attn_src,
    const float* __restrict__ attn_dst, float* __restrict__ a_src,
    float* __restrict__ a_dst, int N) {
    int g = blockIdx.x * 256 + threadIdx.x;
    int n = g >> 2, h = g & 3;
    if (n >= N) return;
    const f16* f = feat16 + (size_t)n * HD + h * D;
    const float* w1 = attn_src + h * D;
    const float* w2 = attn_dst + h * D;
    float s1 = 0.f, s2 = 0.f;
#pragma unroll
    for (int d = 0; d < D; d += 2) {
        f16x2 fv = *(const f16x2*)(f + d);
        float f0 = (float)fv.x, f1 = (float)fv.y;
        s1 += f0 * w1[d] + f1 * w1[d + 1];
        s2 += f0 * w2[d] + f1 * w2[d + 1];
    }
    a_src[n * H + h] = s1;
    a_dst[n * H + h] = s2;
}

// ---------------- K2a: in-degree count
__global__ __launch_bounds__(256) void k_count(const int* __restrict__ dst,
                                               int* __restrict__ deg, int E) {
    int e = blockIdx.x * 256 + threadIdx.x;
    if (e < E) atomicAdd(deg + dst[e], 1);
}

// ---------------- K2b: scan, block partial sums (1024 elems / block)
__global__ __launch_bounds__(256) void k_scan_partial(
    const int* __restrict__ deg, int* __restrict__ partial, int N) {
    __shared__ int sdata[256];
    int t = threadIdx.x;
    int base = blockIdx.x * 1024 + t * 4;
    int s = 0;
#pragma unroll
    for (int j = 0; j < 4; ++j) { int i = base + j; if (i < N) s += deg[i]; }
    sdata[t] = s;
    __syncthreads();
    for (int off = 128; off > 0; off >>= 1) {
        if (t < off) sdata[t] += sdata[t + off];
        __syncthreads();
    }
    if (t == 0) partial[blockIdx.x] = sdata[0];
}

// ---------------- K2c: scan top level (single block), exclusive over partials
__global__ __launch_bounds__(256) void k_scan_top(
    int* __restrict__ partial, int* __restrict__ offs, int nb, int N) {
    __shared__ int sdata[256];
    int t = threadIdx.x;
    int v = (t < nb) ? partial[t] : 0;
    sdata[t] = v;
    __syncthreads();
    for (int off = 1; off < 256; off <<= 1) {
        int add = (t >= off) ? sdata[t - off] : 0;
        __syncthreads();
        sdata[t] += add;
        __syncthreads();
    }
    int excl = (t == 0) ? 0 : sdata[t - 1];
    if (t < nb) partial[t] = excl;
    if (t == nb - 1) offs[N] = sdata[t];   // total = E
}

// ---------------- K2d: final scan; offs aliases deg (in-place, block-local)
__global__ __launch_bounds__(256) void k_scan_final(
    int* __restrict__ deg_offs, const int* __restrict__ partial,
    int* __restrict__ cursor, int N) {
    __shared__ int sdata[256];
    int t = threadIdx.x;
    int base = blockIdx.x * 1024 + t * 4;
    int v[4]; int s = 0;
#pragma unroll
    for (int j = 0; j < 4; ++j) { int i = base + j; v[j] = (i < N) ? deg_offs[i] : 0; s += v[j]; }
    sdata[t] = s;
    __syncthreads();
    for (int off = 1; off < 256; off <<= 1) {
        int add = (t >= off) ? sdata[t - off] : 0;
        __syncthreads();
        sdata[t] += add;
        __syncthreads();
    }
    int excl = partial[blockIdx.x] + ((t == 0) ? 0 : sdata[t - 1]);
#pragma unroll
    for (int j = 0; j < 4; ++j) {
        int i = base + j;
        if (i < N) { deg_offs[i] = excl; cursor[i] = excl; excl += v[j]; }
    }
}

// ---------------- K3: per-edge logits -> exp -> 16B record scatter (2 edges/thread)
__global__ __launch_bounds__(256) void k_edge_fill(
    const float* __restrict__ edge_inputs, const int* __restrict__ src,
    const int* __restrict__ dst, const float* __restrict__ w_eh,
    const float* __restrict__ a_src, const float* __restrict__ a_dst,
    int* __restrict__ cursor, float4* __restrict__ rec, int E) {
    __shared__ float weh_s[EDGE_F * H];
    if (threadIdx.x < EDGE_F * H) weh_s[threadIdx.x] = w_eh[threadIdx.x];
    __syncthreads();

    int base = blockIdx.x * 512 + threadIdx.x;
#pragma unroll
    for (int j = 0; j < 2; ++j) {
        int e = base + j * 256;
        if (e >= E) continue;

        const float* x = edge_inputs + (long)e * EDGE_F;
        float ae[H] = {0.f, 0.f, 0.f, 0.f};
#pragma unroll
        for (int k = 0; k < EDGE_F; ++k) {
            float xv = x[k];
#pragma unroll
            for (int h = 0; h < H; ++h) ae[h] += xv * weh_s[k * H + h];
        }
        int s = src[e], d = dst[e];
        float4 as = *(const float4*)(a_src + s * H);
        float4 ad = *(const float4*)(a_dst + d * H);
        float ev[H];
        ev[0] = as.x + ad.x + ae[0];
        ev[1] = as.y + ad.y + ae[1];
        ev[2] = as.z + ad.z + ae[2];
        ev[3] = as.w + ad.w + ae[3];
#pragma unroll
        for (int h = 0; h < H; ++h) {
            float t = ev[h];
            t = t > 0.f ? t : NEG_SLOPE * t;
            ev[h] = __expf(t);
        }
        int pos = atomicAdd(cursor + d, 1);
        ExPack p;
        p.h = (f16x4){(f16)ev[0], (f16)ev[1], (f16)ev[2], (f16)ev[3]};
        float4 r;
        r.x = __int_as_float(s);
        r.y = p.f.x;
        r.z = p.f.y;
        r.w = 0.f;
        rec[pos] = r;
    }
}

// ---------------- K4: per-dst aggregation; wave/node, lane = 2 adjacent cols
__global__ __launch_bounds__(256) void k_aggr(
    const f16* __restrict__ feat16, const float4* __restrict__ rec,
    const int* __restrict__ offs, float* __restrict__ out, int N) {
    int wave = threadIdx.x >> 6;
    int lane = threadIdx.x & 63;
    int n = blockIdx.x * 4 + wave;
    if (n >= N) return;
    int beg = offs[n], end = offs[n + 1];
    if (end <= beg) return;                 // no in-edges: out keeps res+bias
    int h = lane >> 4;                      // head of cols {2l, 2l+1}
    size_t c0 = (size_t)2 * lane;
    float num0 = 0.f, num1 = 0.f, den = 0.f;
    int i = beg;
    for (; i + 3 < end; i += 4) {
        float4 r0 = rec[i], r1 = rec[i + 1], r2 = rec[i + 2], r3 = rec[i + 3];
        int s0 = __float_as_int(r0.x), s1 = __float_as_int(r1.x);
        int s2 = __float_as_int(r2.x), s3 = __float_as_int(r3.x);
        f16x2 f0 = *(const f16x2*)(feat16 + (size_t)s0 * HD + c0);
        f16x2 f1 = *(const f16x2*)(feat16 + (size_t)s1 * HD + c0);
        f16x2 f2 = *(const f16x2*)(feat16 + (size_t)s2 * HD + c0);
        f16x2 f3 = *(const f16x2*)(feat16 + (size_t)s3 * HD + c0);
        ExPack p0, p1, p2, p3;
        p0.f = make_float2(r0.y, r0.z);
        p1.f = make_float2(r1.y, r1.z);
        p2.f = make_float2(r2.y, r2.z);
        p3.f = make_float2(r3.y, r3.z);
        float e0 = (float)p0.h[h], e1 = (float)p1.h[h];
        float e2 = (float)p2.h[h], e3 = (float)p3.h[h];
        num0 += e0 * (float)f0.x + e1 * (float)f1.x + e2 * (float)f2.x + e3 * (float)f3.x;
        num1 += e0 * (float)f0.y + e1 * (float)f1.y + e2 * (float)f2.y + e3 * (float)f3.y;
        den += e0 + e1 + e2 + e3;
    }
    for (; i < end; ++i) {
        float4 r0 = rec[i];
        int s0 = __float_as_int(r0.x);
        f16x2 f0 = *(const f16x2*)(feat16 + (size_t)s0 * HD + c0);
        ExPack p0;
        p0.f = make_float2(r0.y, r0.z);
        float e0 = (float)p0.h[h];
        num0 += e0 * (float)f0.x;
        num1 += e0 * (float)f0.y;
        den += e0;
    }
    float inv = 1.f / den;
    size_t o = (size_t)n * HD + c0;
    float2 v = *(float2*)(out + o);
    v.x += num0 * inv;
    v.y += num1 * inv;
    *(float2*)(out + o) = v;
}

extern "C" void kernel_launch(void* const* d_in, const int* in_sizes, int n_in,
                              void* d_out, int out_size, void* d_ws, size_t ws_size,
                              hipStream_t stream) {
    const float* node_inputs = (const float*)d_in[0];
    const float* edge_inputs = (const float*)d_in[1];
    const int*   src         = (const int*)d_in[2];
    const int*   dst         = (const int*)d_in[3];
    const float* W_fc        = (const float*)d_in[4];
    const float* attn_src_p  = (const float*)d_in[5];
    const float* attn_dst_p  = (const float*)d_in[6];
    const float* W_edge      = (const float*)d_in[7];
    const float* attn_edge_p = (const float*)d_in[8];
    const float* W_res       = (const float*)d_in[9];
    const float* bias_p      = (const float*)d_in[10];

    int N = in_sizes[0] / NNODES_FEAT;   // 100000
    int E = in_sizes[2];                 // 1600000

    float* out = (float*)d_out;

    // ---- workspace layout (rec 16B-aligned by construction) ----
    f16*    feat16  = (f16*)d_ws;                          // N*128 halves
    float4* rec     = (float4*)(feat16 + (size_t)N * HD);  // E * 16B
    f16*    Wt      = (f16*)(rec + (size_t)E);             // 256*128 halves
    float*  a_src   = (float*)(Wt + 256 * 128);            // N*4
    float*  a_dst   = a_src + (size_t)N * H;               // N*4
    float*  w_eh    = a_dst + (size_t)N * H;               // 64
    int*    deg     = (int*)(w_eh + 64);                   // N+2 (becomes offs)
    int*    offs    = deg;                                 // alias
    int*    cursor  = deg + (N + 2);                       // N
    int*    partial = cursor + N;                          // 128

    hipMemsetAsync(deg, 0, (size_t)(N + 2) * sizeof(int), stream);

    // precompute small tensors
    k_wedge<<<1, 64, 0, stream>>>(W_edge, attn_edge_p, w_eh);
    k_wt<<<(256 * 128) / 256, 256, 0, stream>>>(W_fc, W_res, Wt);

    // MFMA GEMM (stages fp32 A directly) -> feat16 (cb=0), out = res + bias (cb=1)
    dim3 g1((N + 63) / 64, 2);
    k_gemm_mfma<<<g1, 256, 0, stream>>>(node_inputs, Wt, bias_p, feat16, out, N);

    // per-node attention logits
    int nb = (N * H + 255) / 256;
    k_attn_nodes<<<nb, 256, 0, stream>>>(feat16, attn_src_p, attn_dst_p, a_src, a_dst, N);

    // CSR by dst
    int eb = (E + 255) / 256;
    k_count<<<eb, 256, 0, stream>>>(dst, deg, E);
    int sb = (N + 1023) / 1024;   // 98 blocks
    k_scan_partial<<<sb, 256, 0, stream>>>(deg, partial, N);
    k_scan_top<<<1, 256, 0, stream>>>(partial, offs, sb, N);
    k_scan_final<<<sb, 256, 0, stream>>>(deg, partial, cursor, N);

    // edge logits -> exp, scattered into dst-bucketed 16B records
    int eb2 = (E + 511) / 512;
    k_edge_fill<<<eb2, 256, 0, stream>>>(edge_inputs, src, dst, w_eh, a_src, a_dst,
                                         cursor, rec, E);

    // aggregation
    int ab = (N + 3) / 4;
    k_aggr<<<ab, 256, 0, stream>>>(feat16, rec, offs, out, N);
}